// Round 11
// baseline (18.101 us; speedup 1.0000x reference)
//
#include <hip/hip_runtime.h>

#define FEAT 128
#define HID 32
#define BLOCK 512        // 8 waves
#define GRID 256         // 1 persistent block per CU

typedef __attribute__((ext_vector_type(8))) __bf16 bf16x8;
typedef __attribute__((ext_vector_type(8))) unsigned short ushortx8;
typedef __attribute__((ext_vector_type(4))) float floatx4;

static __device__ inline unsigned short f2u(float f) {
    return __builtin_bit_cast(unsigned short, (__bf16)f);   // RTNE, pairs fuse to v_cvt_pk_bf16_f32
}
static __device__ inline float fsig(float v) {
    return __builtin_amdgcn_rcpf(1.f + __expf(-v));
}
static __device__ inline float ftanh(float v) {
    return 1.f - 2.f * __builtin_amdgcn_rcpf(__expf(2.f * v) + 1.f);
}

// MFMA + gate epilogue + store for one 16-row strip (af = 4 bf16x8 A-frags).
static __device__ inline void do_strip(
    const bf16x8* af, const unsigned short* sWf, int l, int n0, int g,
    float bz0, float bz1, float bh0, float bh1,
    float wl0, float wl1, float blv,
    float* __restrict__ out, int strip, int nstrips)
{
    floatx4 acc[4] = {{0,0,0,0},{0,0,0,0},{0,0,0,0},{0,0,0,0}};
    #pragma unroll
    for (int s = 0; s < 4; ++s) {
        #pragma unroll
        for (int nt = 0; nt < 4; ++nt) {
            bf16x8 bfrag = __builtin_bit_cast(bf16x8,
                *(const ushortx8*)&sWf[((s * 4 + nt) * 64 + l) * 8]);
            acc[nt] = __builtin_amdgcn_mfma_f32_16x16x32_bf16(af[s], bfrag, acc[nt], 0, 0, 0);
        }
    }
    float4 res; float* resp = &res.x;
    #pragma unroll
    for (int r = 0; r < 4; ++r) {
        float z0 = fsig(acc[0][r] + bz0);
        float z1 = fsig(acc[1][r] + bz1);
        float h0 = ftanh(acc[2][r] + bh0);
        float h1 = ftanh(acc[3][r] + bh1);
        float v0 = (1.f - z0) * h0; v0 = v0 > 0.f ? v0 : 0.f;
        float v1 = (1.f - z1) * h1; v1 = v1 > 0.f ? v1 : 0.f;
        float sm = v0 * wl0 + v1 * wl1;
        sm += __shfl_xor(sm, 1);
        sm += __shfl_xor(sm, 2);
        sm += __shfl_xor(sm, 4);
        sm += __shfl_xor(sm, 8);
        resp[r] = sm + blv;
    }
    if (strip < nstrips && n0 == 0)
        *(float4*)&out[(long long)strip * 16 + g * 4] = res;   // 16|strip*16, g*4%4==0
}

// Persistent: 256 blocks (1/CU), 8 waves each. Wave owns strips b+256*(wid+8k),
// k=0..2 (bijection over 0..6143); the 106 leftover strips (6144+b, b<106) go to
// wave (b&7) of block b. W staged ONCE per CU; all 24 A-loads issued back-to-back
// (deep MLP), converted progressively (counted-vmcnt waits overlap VALU with the
// stream); post-barrier is pure MFMA+epilogue.
__global__ __launch_bounds__(BLOCK, 2) void dcrnn_pers(
    const float* __restrict__ x,
    const float* __restrict__ Wz, const float* __restrict__ Wh,
    const float* __restrict__ bz, const float* __restrict__ bh,
    const float* __restrict__ wl, const float* __restrict__ bl,
    float* __restrict__ out, int n_nodes)
{
    __shared__ unsigned short sWf[16 * 64 * 8];   // 16 KB, fragment-linear

    const int tid = threadIdx.x;
    const int wid = tid >> 6;    // 0..7
    const int l   = tid & 63;
    const int n0  = l & 15;      // A row within strip / B col / C col
    const int g   = l >> 4;      // k-group / C row-group
    const int b   = blockIdx.x;
    const int nstrips = (n_nodes + 15) >> 4;      // 6250

    // ---- (a) W combine + stage FIRST (oldest in VMEM queue -> its consumers
    //      wait a counted vmcnt that does NOT drain the A stream) ----
    // W shape (2,1,160,32): [d,0,k,col] at d*5120 + k*32 + col; k<128 is x-part.
    // sWf[((s*4+nt)*64 + lane)*8 + j] == Wc[k=s*32+(lane>>4)*8+j][o=nt*16+(lane&15)]
    #pragma unroll
    for (int p = 0; p < 2; ++p) {
        const int e8 = p * BLOCK + tid;           // 0..1023
        const int f = e8 >> 6, wl_ = e8 & 63;
        const int nt = f & 3, sk = f >> 2;
        const int kbase = sk * 32 + (wl_ >> 4) * 8;
        const int o = nt * 16 + (wl_ & 15);
        const float* __restrict__ W = (o < HID) ? Wz : Wh;   // wave-uniform
        const int col = o & 31;
        ushortx8 v;
        #pragma unroll
        for (int j = 0; j < 8; ++j) {
            const int a = (kbase + j) * HID + col;
            v[j] = f2u(W[a] + W[5120 + a]);
        }
        *(ushortx8*)&sWf[e8 * 8] = v;
    }

    // ---- (b) strip ids (bijection; see header comment) ----
    const int s0 = b + 256 * wid;
    const int s1 = b + 256 * (wid + 8);
    const int s2 = b + 256 * (wid + 16);
    const int rem = nstrips - 256 * 24;           // 106 for N=100000
    const int sx = (b < rem && wid == (b & 7)) ? 256 * 24 + b : -1;

    // ---- (c) issue ALL 24 A-loads back-to-back (deep MLP, HBM-saturating) ----
    const float* xr0 = x + ((long long)((s0 < nstrips) ? s0 : 0) * 16 + n0) * FEAT + g * 8;
    const float* xr1 = x + ((long long)((s1 < nstrips) ? s1 : 0) * 16 + n0) * FEAT + g * 8;
    const float* xr2 = x + ((long long)((s2 < nstrips) ? s2 : 0) * 16 + n0) * FEAT + g * 8;
    float4 fa0[8], fa1[8], fa2[8];
    #pragma unroll
    for (int s = 0; s < 4; ++s) {
        fa0[2*s] = *(const float4*)(xr0 + s*32); fa0[2*s+1] = *(const float4*)(xr0 + s*32 + 4);
    }
    #pragma unroll
    for (int s = 0; s < 4; ++s) {
        fa1[2*s] = *(const float4*)(xr1 + s*32); fa1[2*s+1] = *(const float4*)(xr1 + s*32 + 4);
    }
    #pragma unroll
    for (int s = 0; s < 4; ++s) {
        fa2[2*s] = *(const float4*)(xr2 + s*32); fa2[2*s+1] = *(const float4*)(xr2 + s*32 + 4);
    }

    // ---- (d) progressive fp32->bf16 (counted-vmcnt waits overlap the stream) ----
    bf16x8 af0[4], af1[4], af2[4];
    #pragma unroll
    for (int s = 0; s < 4; ++s) {
        ushortx8 v;
        v[0]=f2u(fa0[2*s].x); v[1]=f2u(fa0[2*s].y); v[2]=f2u(fa0[2*s].z); v[3]=f2u(fa0[2*s].w);
        v[4]=f2u(fa0[2*s+1].x); v[5]=f2u(fa0[2*s+1].y); v[6]=f2u(fa0[2*s+1].z); v[7]=f2u(fa0[2*s+1].w);
        af0[s] = __builtin_bit_cast(bf16x8, v);
    }
    #pragma unroll
    for (int s = 0; s < 4; ++s) {
        ushortx8 v;
        v[0]=f2u(fa1[2*s].x); v[1]=f2u(fa1[2*s].y); v[2]=f2u(fa1[2*s].z); v[3]=f2u(fa1[2*s].w);
        v[4]=f2u(fa1[2*s+1].x); v[5]=f2u(fa1[2*s+1].y); v[6]=f2u(fa1[2*s+1].z); v[7]=f2u(fa1[2*s+1].w);
        af1[s] = __builtin_bit_cast(bf16x8, v);
    }
    #pragma unroll
    for (int s = 0; s < 4; ++s) {
        ushortx8 v;
        v[0]=f2u(fa2[2*s].x); v[1]=f2u(fa2[2*s].y); v[2]=f2u(fa2[2*s].z); v[3]=f2u(fa2[2*s].w);
        v[4]=f2u(fa2[2*s+1].x); v[5]=f2u(fa2[2*s+1].y); v[6]=f2u(fa2[2*s+1].z); v[7]=f2u(fa2[2*s+1].w);
        af2[s] = __builtin_bit_cast(bf16x8, v);
    }

    __syncthreads();   // trivial drain: everything already consumed

    // ---- (e) epilogue constants ----
    const float bz0 = bz[n0], bz1 = bz[n0 + 16];
    const float bh0 = bh[n0], bh1 = bh[n0 + 16];
    const float wl0 = wl[n0], wl1 = wl[n0 + 16];
    const float blv = bl[0];

    // ---- (f) extra strip's loads issued now (hide under s0..s2 compute) ----
    float4 fx[8];
    if (sx >= 0) {
        const float* xrx = x + ((long long)sx * 16 + n0) * FEAT + g * 8;
        #pragma unroll
        for (int s = 0; s < 4; ++s) {
            fx[2*s] = *(const float4*)(xrx + s*32); fx[2*s+1] = *(const float4*)(xrx + s*32 + 4);
        }
    }

    // ---- (g) compute ----
    do_strip(af0, sWf, l, n0, g, bz0, bz1, bh0, bh1, wl0, wl1, blv, out, s0, nstrips);
    do_strip(af1, sWf, l, n0, g, bz0, bz1, bh0, bh1, wl0, wl1, blv, out, s1, nstrips);
    do_strip(af2, sWf, l, n0, g, bz0, bz1, bh0, bh1, wl0, wl1, blv, out, s2, nstrips);
    if (sx >= 0) {
        bf16x8 afx[4];
        #pragma unroll
        for (int s = 0; s < 4; ++s) {
            ushortx8 v;
            v[0]=f2u(fx[2*s].x); v[1]=f2u(fx[2*s].y); v[2]=f2u(fx[2*s].z); v[3]=f2u(fx[2*s].w);
            v[4]=f2u(fx[2*s+1].x); v[5]=f2u(fx[2*s+1].y); v[6]=f2u(fx[2*s+1].z); v[7]=f2u(fx[2*s+1].w);
            afx[s] = __builtin_bit_cast(bf16x8, v);
        }
        do_strip(afx, sWf, l, n0, g, bz0, bz1, bh0, bh1, wl0, wl1, blv, out, sx, nstrips);
    }
}

extern "C" void kernel_launch(void* const* d_in, const int* in_sizes, int n_in,
                              void* d_out, int out_size, void* d_ws, size_t ws_size,
                              hipStream_t stream) {
    // inputs: 0:x 1:edge_index(dead) 2:edge_weight(dead) 3:W_z 4:b_z 5:W_r(dead)
    //         6:b_r(dead) 7:W_h 8:b_h 9:W_lin 10:b_lin
    const float* x    = (const float*)d_in[0];
    const float* Wz   = (const float*)d_in[3];
    const float* bz   = (const float*)d_in[4];
    const float* Wh   = (const float*)d_in[7];
    const float* bh   = (const float*)d_in[8];
    const float* Wlin = (const float*)d_in[9];
    const float* blin = (const float*)d_in[10];
    float* out = (float*)d_out;

    const int n_nodes = in_sizes[0] / FEAT;
    dcrnn_pers<<<GRID, BLOCK, 0, stream>>>(x, Wz, Wh, bz, bh, Wlin, blin, out, n_nodes);
}

// Round 12
// 17.004 us; speedup vs baseline: 1.0645x; 1.0645x over previous
//
#include <hip/hip_runtime.h>

#define FEAT 128
#define HID 32
#define BLOCK 512        // 8 waves
#define GRID 512         // exactly 2 blocks per CU, per-CU strip count balanced

typedef __attribute__((ext_vector_type(8))) __bf16 bf16x8;
typedef __attribute__((ext_vector_type(8))) unsigned short ushortx8;
typedef __attribute__((ext_vector_type(4))) float floatx4;

static __device__ inline unsigned short f2u(float f) {
    return __builtin_bit_cast(unsigned short, (__bf16)f);   // RTNE, pairs fuse to v_cvt_pk_bf16_f32
}
static __device__ inline float fsig(float v) {
    return __builtin_amdgcn_rcpf(1.f + __expf(-v));
}
static __device__ inline float ftanh(float v) {
    return 1.f - 2.f * __builtin_amdgcn_rcpf(__expf(2.f * v) + 1.f);
}

// R9 internals, rebalanced grid: 512 blocks x (12 or 13) contiguous strips.
// 6250 = 512*12 + 106: blocks 0..105 take 13 strips, 106..511 take 12.
// Wave wid runs strip base+wid always, and base+8+wid when 8+wid < count
// (waves 0..3 or 0..4) -> per-CU strips 24-26 instead of R9's 16-or-32.
__global__ __launch_bounds__(BLOCK, 4) void dcrnn_bal(
    const float* __restrict__ x,
    const float* __restrict__ Wz, const float* __restrict__ Wh,
    const float* __restrict__ bz, const float* __restrict__ bh,
    const float* __restrict__ wl, const float* __restrict__ bl,
    float* __restrict__ out, int n_nodes)
{
    __shared__ unsigned short sWf[16 * 64 * 8];   // 16 KB, fragment-linear

    const int tid = threadIdx.x;
    const int wid = tid >> 6;    // 0..7
    const int l   = tid & 63;
    const int n0  = l & 15;      // A row within strip / B col / C col
    const int g   = l >> 4;      // k-group / C row-group

    const int nstrips = (n_nodes + 15) >> 4;      // 6250
    const int q = nstrips >> 9;                   // nstrips / 512
    const int r = nstrips - (q << 9);             // nstrips % 512
    const int b = blockIdx.x;
    const int cnt  = q + (b < r ? 1 : 0);
    const int base = b * q + (b < r ? b : r);

    const int s1 = base + wid;                    // wid < 8 <= q -> always valid
    const int s2 = base + 8 + wid;
    const bool act2 = (8 + wid) < cnt;

    // ---- (a) issue strip-1 A loads (HBM latency starts now) ----
    const long long row1 = (long long)s1 * 16 + n0;
    const float* xr1 = x + row1 * FEAT + g * 8;
    float4 xa1[4], xb1[4];
    #pragma unroll
    for (int s = 0; s < 4; ++s) {
        xa1[s] = *(const float4*)(xr1 + s * 32);
        xb1[s] = *(const float4*)(xr1 + s * 32 + 4);
    }

    // ---- (b) cooperative W combine + stage ----
    // W shape (2,1,160,32): [d,0,k,col] at d*5120 + k*32 + col; k<128 is the x-part.
    // sWf[((s*4+nt)*64 + lane)*8 + j] == Wc[k = s*32+(lane>>4)*8+j][o = nt*16+(lane&15)]
    #pragma unroll
    for (int p = 0; p < 2; ++p) {
        const int e8 = p * BLOCK + tid;           // ushortx8 index, 0..1023
        const int f = e8 >> 6, wl_ = e8 & 63;
        const int nt = f & 3, sk = f >> 2;
        const int kbase = sk * 32 + (wl_ >> 4) * 8;
        const int o = nt * 16 + (wl_ & 15);
        const float* __restrict__ W = (o < HID) ? Wz : Wh;   // wave-uniform
        const int col = o & 31;
        ushortx8 v;
        #pragma unroll
        for (int j = 0; j < 8; ++j) {
            const int a = (kbase + j) * HID + col;
            v[j] = f2u(W[a] + W[5120 + a]);
        }
        *(ushortx8*)&sWf[e8 * 8] = v;
    }

    // ---- (c) epilogue constants (once per wave) ----
    const float bz0 = bz[n0], bz1 = bz[n0 + 16];
    const float bh0 = bh[n0], bh1 = bh[n0 + 16];
    const float wl0 = wl[n0], wl1 = wl[n0 + 16];
    const float blv = bl[0];

    // ---- (d) strip-1 fp32 -> bf16 frags (frees the fp32 regs) ----
    bf16x8 af1[4];
    #pragma unroll
    for (int s = 0; s < 4; ++s) {
        ushortx8 av;
        av[0] = f2u(xa1[s].x); av[1] = f2u(xa1[s].y); av[2] = f2u(xa1[s].z); av[3] = f2u(xa1[s].w);
        av[4] = f2u(xb1[s].x); av[5] = f2u(xb1[s].y); av[6] = f2u(xb1[s].z); av[7] = f2u(xb1[s].w);
        af1[s] = __builtin_bit_cast(bf16x8, av);
    }

    // ---- (e) issue strip-2 A loads (hide under strip-1 compute + TLP) ----
    const long long row2 = (long long)(act2 ? s2 : s1) * 16 + n0;
    const float* xr2 = x + row2 * FEAT + g * 8;
    float4 xa2[4], xb2[4];
    #pragma unroll
    for (int s = 0; s < 4; ++s) {
        xa2[s] = *(const float4*)(xr2 + s * 32);
        xb2[s] = *(const float4*)(xr2 + s * 32 + 4);
    }

    __syncthreads();   // the ONLY barrier

    // ---- (f) strip-1: MFMA + epilogue ----
    {
        floatx4 acc[4] = {{0,0,0,0},{0,0,0,0},{0,0,0,0},{0,0,0,0}};
        #pragma unroll
        for (int s = 0; s < 4; ++s) {
            #pragma unroll
            for (int nt = 0; nt < 4; ++nt) {
                bf16x8 bfrag = __builtin_bit_cast(bf16x8,
                    *(const ushortx8*)&sWf[((s * 4 + nt) * 64 + l) * 8]);
                acc[nt] = __builtin_amdgcn_mfma_f32_16x16x32_bf16(af1[s], bfrag, acc[nt], 0, 0, 0);
            }
        }
        float4 res; float* resp = &res.x;
        #pragma unroll
        for (int rr = 0; rr < 4; ++rr) {
            float z0 = fsig(acc[0][rr] + bz0);
            float z1 = fsig(acc[1][rr] + bz1);
            float h0 = ftanh(acc[2][rr] + bh0);
            float h1 = ftanh(acc[3][rr] + bh1);
            float v0 = (1.f - z0) * h0; v0 = v0 > 0.f ? v0 : 0.f;
            float v1 = (1.f - z1) * h1; v1 = v1 > 0.f ? v1 : 0.f;
            float sm = v0 * wl0 + v1 * wl1;
            sm += __shfl_xor(sm, 1);
            sm += __shfl_xor(sm, 2);
            sm += __shfl_xor(sm, 4);
            sm += __shfl_xor(sm, 8);
            resp[rr] = sm + blv;
        }
        if (n0 == 0)
            *(float4*)&out[(long long)s1 * 16 + g * 4] = res;
    }

    // ---- (g) strip-2: convert + MFMA + epilogue (wave-uniform predicate) ----
    if (act2) {
        floatx4 acc[4] = {{0,0,0,0},{0,0,0,0},{0,0,0,0},{0,0,0,0}};
        #pragma unroll
        for (int s = 0; s < 4; ++s) {
            ushortx8 av;
            av[0] = f2u(xa2[s].x); av[1] = f2u(xa2[s].y); av[2] = f2u(xa2[s].z); av[3] = f2u(xa2[s].w);
            av[4] = f2u(xb2[s].x); av[5] = f2u(xb2[s].y); av[6] = f2u(xb2[s].z); av[7] = f2u(xb2[s].w);
            bf16x8 afrag = __builtin_bit_cast(bf16x8, av);
            #pragma unroll
            for (int nt = 0; nt < 4; ++nt) {
                bf16x8 bfrag = __builtin_bit_cast(bf16x8,
                    *(const ushortx8*)&sWf[((s * 4 + nt) * 64 + l) * 8]);
                acc[nt] = __builtin_amdgcn_mfma_f32_16x16x32_bf16(afrag, bfrag, acc[nt], 0, 0, 0);
            }
        }
        float4 res; float* resp = &res.x;
        #pragma unroll
        for (int rr = 0; rr < 4; ++rr) {
            float z0 = fsig(acc[0][rr] + bz0);
            float z1 = fsig(acc[1][rr] + bz1);
            float h0 = ftanh(acc[2][rr] + bh0);
            float h1 = ftanh(acc[3][rr] + bh1);
            float v0 = (1.f - z0) * h0; v0 = v0 > 0.f ? v0 : 0.f;
            float v1 = (1.f - z1) * h1; v1 = v1 > 0.f ? v1 : 0.f;
            float sm = v0 * wl0 + v1 * wl1;
            sm += __shfl_xor(sm, 1);
            sm += __shfl_xor(sm, 2);
            sm += __shfl_xor(sm, 4);
            sm += __shfl_xor(sm, 8);
            resp[rr] = sm + blv;
        }
        if (n0 == 0)
            *(float4*)&out[(long long)s2 * 16 + g * 4] = res;
    }
}

extern "C" void kernel_launch(void* const* d_in, const int* in_sizes, int n_in,
                              void* d_out, int out_size, void* d_ws, size_t ws_size,
                              hipStream_t stream) {
    // inputs: 0:x 1:edge_index(dead) 2:edge_weight(dead) 3:W_z 4:b_z 5:W_r(dead)
    //         6:b_r(dead) 7:W_h 8:b_h 9:W_lin 10:b_lin
    const float* x    = (const float*)d_in[0];
    const float* Wz   = (const float*)d_in[3];
    const float* bz   = (const float*)d_in[4];
    const float* Wh   = (const float*)d_in[7];
    const float* bh   = (const float*)d_in[8];
    const float* Wlin = (const float*)d_in[9];
    const float* blin = (const float*)d_in[10];
    float* out = (float*)d_out;

    const int n_nodes = in_sizes[0] / FEAT;
    dcrnn_bal<<<GRID, BLOCK, 0, stream>>>(x, Wz, Wh, bz, bh, Wlin, blin, out, n_nodes);
}

// Round 13
// 16.889 us; speedup vs baseline: 1.0718x; 1.0068x over previous
//
#include <hip/hip_runtime.h>

#define FEAT 128
#define HID 32
#define BLOCK 512        // 8 waves; TWO 16-row strips per wave
#define SPB 16           // strips per block

typedef __attribute__((ext_vector_type(8))) __bf16 bf16x8;
typedef __attribute__((ext_vector_type(8))) unsigned short ushortx8;
typedef __attribute__((ext_vector_type(4))) float floatx4;

static __device__ inline unsigned short f2u(float f) {
    return __builtin_bit_cast(unsigned short, (__bf16)f);   // RTNE, pairs fuse to v_cvt_pk_bf16_f32
}
static __device__ inline float fsig(float v) {
    return __builtin_amdgcn_rcpf(1.f + __expf(-v));
}
static __device__ inline float ftanh(float v) {
    return 1.f - 2.f * __builtin_amdgcn_rcpf(__expf(2.f * v) + 1.f);
}

// BEST VARIANT (R9, 16.87 us): 8 waves x 2 strips/wave, W combined + staged
// once per 16 strips (391 blocks). Staggered schedule: s1 loads -> W stage ->
// s1->bf16 (frees fp32 regs) -> s2 loads -> barrier -> compute s1 -> compute s2.
__global__ __launch_bounds__(BLOCK, 4) void dcrnn_w2(
    const float* __restrict__ x,
    const float* __restrict__ Wz, const float* __restrict__ Wh,
    const float* __restrict__ bz, const float* __restrict__ bh,
    const float* __restrict__ wl, const float* __restrict__ bl,
    float* __restrict__ out, int n_nodes)
{
    __shared__ unsigned short sWf[16 * 64 * 8];   // 16 KB, fragment-linear

    const int tid = threadIdx.x;
    const int wid = tid >> 6;    // 0..7
    const int l   = tid & 63;
    const int n0  = l & 15;      // A row within strip / B col / C col
    const int g   = l >> 4;      // k-group / C row-group

    const int nstrips = (n_nodes + 15) >> 4;      // 6250
    const int base = blockIdx.x * SPB;
    const int s1 = base + wid;
    const int s2 = base + wid + 8;
    const bool act1 = s1 < nstrips;
    const bool act2 = s2 < nstrips;

    // ---- (a) issue strip-1 A loads (HBM latency starts now) ----
    const long long row1 = (long long)(act1 ? s1 : 0) * 16 + n0;
    const float* xr1 = x + row1 * FEAT + g * 8;
    float4 xa1[4], xb1[4];
    #pragma unroll
    for (int s = 0; s < 4; ++s) {
        xa1[s] = *(const float4*)(xr1 + s * 32);
        xb1[s] = *(const float4*)(xr1 + s * 32 + 4);
    }

    // ---- (b) cooperative W combine + stage, once per 16 strips ----
    // W shape (2,1,160,32): [d,0,k,col] at d*5120 + k*32 + col; k<128 is the x-part.
    // sWf[((s*4+nt)*64 + lane)*8 + j] == Wc[k = s*32+(lane>>4)*8+j][o = nt*16+(lane&15)]
    #pragma unroll
    for (int p = 0; p < 2; ++p) {
        const int e8 = p * BLOCK + tid;           // ushortx8 index, 0..1023
        const int f = e8 >> 6, wl_ = e8 & 63;
        const int nt = f & 3, sk = f >> 2;
        const int kbase = sk * 32 + (wl_ >> 4) * 8;
        const int o = nt * 16 + (wl_ & 15);
        const float* __restrict__ W = (o < HID) ? Wz : Wh;   // wave-uniform
        const int col = o & 31;
        ushortx8 v;
        #pragma unroll
        for (int j = 0; j < 8; ++j) {
            const int a = (kbase + j) * HID + col;
            v[j] = f2u(W[a] + W[5120 + a]);
        }
        *(ushortx8*)&sWf[e8 * 8] = v;
    }

    // ---- (c) epilogue constants (once per wave) ----
    const float bz0 = bz[n0], bz1 = bz[n0 + 16];
    const float bh0 = bh[n0], bh1 = bh[n0 + 16];
    const float wl0 = wl[n0], wl1 = wl[n0 + 16];
    const float blv = bl[0];

    // ---- (d) strip-1 fp32 -> bf16 frags (frees the fp32 regs) ----
    bf16x8 af1[4];
    #pragma unroll
    for (int s = 0; s < 4; ++s) {
        ushortx8 av;
        av[0] = f2u(xa1[s].x); av[1] = f2u(xa1[s].y); av[2] = f2u(xa1[s].z); av[3] = f2u(xa1[s].w);
        av[4] = f2u(xb1[s].x); av[5] = f2u(xb1[s].y); av[6] = f2u(xb1[s].z); av[7] = f2u(xb1[s].w);
        af1[s] = __builtin_bit_cast(bf16x8, av);
    }

    // ---- (e) issue strip-2 A loads (hide under strip-1 compute + TLP) ----
    const long long row2 = (long long)(act2 ? s2 : 0) * 16 + n0;
    const float* xr2 = x + row2 * FEAT + g * 8;
    float4 xa2[4], xb2[4];
    #pragma unroll
    for (int s = 0; s < 4; ++s) {
        xa2[s] = *(const float4*)(xr2 + s * 32);
        xb2[s] = *(const float4*)(xr2 + s * 32 + 4);
    }

    __syncthreads();   // the ONLY barrier

    // ---- (f) strip-1: MFMA + epilogue ----
    {
        floatx4 acc[4] = {{0,0,0,0},{0,0,0,0},{0,0,0,0},{0,0,0,0}};
        #pragma unroll
        for (int s = 0; s < 4; ++s) {
            #pragma unroll
            for (int nt = 0; nt < 4; ++nt) {
                bf16x8 bfrag = __builtin_bit_cast(bf16x8,
                    *(const ushortx8*)&sWf[((s * 4 + nt) * 64 + l) * 8]);
                acc[nt] = __builtin_amdgcn_mfma_f32_16x16x32_bf16(af1[s], bfrag, acc[nt], 0, 0, 0);
            }
        }
        float4 res; float* resp = &res.x;
        #pragma unroll
        for (int r = 0; r < 4; ++r) {
            float z0 = fsig(acc[0][r] + bz0);
            float z1 = fsig(acc[1][r] + bz1);
            float h0 = ftanh(acc[2][r] + bh0);
            float h1 = ftanh(acc[3][r] + bh1);
            float v0 = (1.f - z0) * h0; v0 = v0 > 0.f ? v0 : 0.f;
            float v1 = (1.f - z1) * h1; v1 = v1 > 0.f ? v1 : 0.f;
            float sm = v0 * wl0 + v1 * wl1;
            sm += __shfl_xor(sm, 1);
            sm += __shfl_xor(sm, 2);
            sm += __shfl_xor(sm, 4);
            sm += __shfl_xor(sm, 8);
            resp[r] = sm + blv;
        }
        if (act1 && n0 == 0) {
            long long m = (long long)s1 * 16 + g * 4;   // m%4==0
            *(float4*)&out[m] = res;
        }
    }

    // ---- (g) strip-2: convert + MFMA + epilogue ----
    {
        floatx4 acc[4] = {{0,0,0,0},{0,0,0,0},{0,0,0,0},{0,0,0,0}};
        #pragma unroll
        for (int s = 0; s < 4; ++s) {
            ushortx8 av;
            av[0] = f2u(xa2[s].x); av[1] = f2u(xa2[s].y); av[2] = f2u(xa2[s].z); av[3] = f2u(xa2[s].w);
            av[4] = f2u(xb2[s].x); av[5] = f2u(xb2[s].y); av[6] = f2u(xb2[s].z); av[7] = f2u(xb2[s].w);
            bf16x8 afrag = __builtin_bit_cast(bf16x8, av);
            #pragma unroll
            for (int nt = 0; nt < 4; ++nt) {
                bf16x8 bfrag = __builtin_bit_cast(bf16x8,
                    *(const ushortx8*)&sWf[((s * 4 + nt) * 64 + l) * 8]);
                acc[nt] = __builtin_amdgcn_mfma_f32_16x16x32_bf16(afrag, bfrag, acc[nt], 0, 0, 0);
            }
        }
        float4 res; float* resp = &res.x;
        #pragma unroll
        for (int r = 0; r < 4; ++r) {
            float z0 = fsig(acc[0][r] + bz0);
            float z1 = fsig(acc[1][r] + bz1);
            float h0 = ftanh(acc[2][r] + bh0);
            float h1 = ftanh(acc[3][r] + bh1);
            float v0 = (1.f - z0) * h0; v0 = v0 > 0.f ? v0 : 0.f;
            float v1 = (1.f - z1) * h1; v1 = v1 > 0.f ? v1 : 0.f;
            float sm = v0 * wl0 + v1 * wl1;
            sm += __shfl_xor(sm, 1);
            sm += __shfl_xor(sm, 2);
            sm += __shfl_xor(sm, 4);
            sm += __shfl_xor(sm, 8);
            resp[r] = sm + blv;
        }
        if (act2 && n0 == 0) {
            long long m = (long long)s2 * 16 + g * 4;   // m%4==0
            *(float4*)&out[m] = res;
        }
    }
}

extern "C" void kernel_launch(void* const* d_in, const int* in_sizes, int n_in,
                              void* d_out, int out_size, void* d_ws, size_t ws_size,
                              hipStream_t stream) {
    // inputs: 0:x 1:edge_index(dead) 2:edge_weight(dead) 3:W_z 4:b_z 5:W_r(dead)
    //         6:b_r(dead) 7:W_h 8:b_h 9:W_lin 10:b_lin
    const float* x    = (const float*)d_in[0];
    const float* Wz   = (const float*)d_in[3];
    const float* bz   = (const float*)d_in[4];
    const float* Wh   = (const float*)d_in[7];
    const float* bh   = (const float*)d_in[8];
    const float* Wlin = (const float*)d_in[9];
    const float* blin = (const float*)d_in[10];
    float* out = (float*)d_out;

    const int n_nodes = in_sizes[0] / FEAT;
    const int nstrips = (n_nodes + 15) / 16;          // 6250
    const int grid = (nstrips + SPB - 1) / SPB;       // 391
    dcrnn_w2<<<grid, BLOCK, 0, stream>>>(x, Wz, Wh, bz, bh, Wlin, blin, out, n_nodes);
}